// Round 2
// 470.481 us; speedup vs baseline: 1.0009x; 1.0009x over previous
//
#include <hip/hip_runtime.h>
#include <hip/hip_bf16.h>

// GNN processor: NL=256, NP=8192, NV=16, B=2.
// R1: factored first edge layer (S/P/E gather trick) + fused MFMA MLPs. 555us.
// R2: 512-thread/MT=2 blocks (43% occ), merged launches. 481us.
// R3: E-GEMM inlined into edge_mlp (64-row blocks, E computed once). 471us.
// R4: rows-per-block doubled (edge: 128 rows/MT=4, node: 64 rows/MT=2).
//     Theory: edge_mlp was L2-BW/latency bound on per-wave B-frag streaming
//     (1 MB/block -> 4.3 GB/dispatch ~ 19 TB/s ~ 55% of L2 ceiling) plus
//     8 full-drain barriers per 64 rows. Doubling rows halves weight traffic
//     and barrier count per row. LDS 70KB -> still 2 blocks/CU.
// R5: identical resubmission of R4 (bench infra failed; no counters returned).

typedef __bf16 bf16;
typedef __bf16 bf16x8 __attribute__((ext_vector_type(8)));
typedef float f32x4 __attribute__((ext_vector_type(4)));

#define MFMA16(a, b, c) __builtin_amdgcn_mfma_f32_16x16x32_bf16((a), (b), (c), 0, 0, 0)

constexpr int kNP = 8192;
constexpr int kNV = 16;

// ---------------- weight packing (single launch, 10 segments) ----------------
// fp32 W[K][N] -> bf16 fragment-ready:
// dst[((nt*kd + ks)*64 + lane)*8 + j] = W[ks*32 + (lane>>4)*8 + j][nt*16 + (lane&15)]
__global__ __launch_bounds__(256) void pack_all(
    const float* __restrict__ e_fw, const float* __restrict__ e_hw,
    const float* __restrict__ e_lw, const float* __restrict__ n_fw,
    const float* __restrict__ n_hw, const float* __restrict__ n_lw,
    bf16* __restrict__ wp) {
  int t = blockIdx.x * 256 + threadIdx.x;  // 0..720895
  const float* src;
  int kd = 8, local;
  if (t < 196608) {            // w_self / w_nb / w_ea from e_fw (768x256)
    src = e_fw + (t >> 16) * 65536; local = t & 65535;
  } else if (t < 262144) { src = e_hw;           local = t - 196608;
  } else if (t < 327680) { src = e_hw + 65536;   local = t - 262144;
  } else if (t < 393216) { src = e_lw;           local = t - 327680;
  } else if (t < 524288) { src = n_fw;           local = t - 393216; kd = 16;
  } else if (t < 589824) { src = n_hw;           local = t - 524288;
  } else if (t < 655360) { src = n_hw + 65536;   local = t - 589824;
  } else               { src = n_lw;             local = t - 655360; }
  int j = local & 7;
  int l = (local >> 3) & 63;
  int r2 = local >> 9;
  int ks = r2 % kd;
  int nt = r2 / kd;
  int k = ks * 32 + ((l >> 4) << 3) + j;
  int n = (nt << 4) + (l & 15);
  wp[t] = (bf16)src[k * 256 + n];
}

// ---------------- MFMA layer primitives ----------------
// 512-thread block = 8 waves: wave w -> row-group rg=w>>2, col-group wc=w&3.
// X: LDS [rows][280] bf16 (K+24 pad). A-frag from LDS, B-frag lane-ordered
// packed global load (1KB coalesced, L2-hot).
// C/D: col = lane&15, row = (lane>>4)*4 + i
template <int KD, int MT>
__device__ __forceinline__ void layer_acc(const bf16* X, int xs,
                                          const bf16* __restrict__ Wp,
                                          const float* __restrict__ bias,
                                          f32x4 (&acc)[MT][4], int rowOff,
                                          int wc) {
  const int lane = threadIdx.x & 63;
  const int q = lane >> 4;
  const int c = lane & 15;
#pragma unroll
  for (int nt = 0; nt < 4; nt++) {
    float bv = bias ? bias[wc * 64 + nt * 16 + c] : 0.0f;
#pragma unroll
    for (int mt = 0; mt < MT; mt++) {
      acc[mt][nt][0] = bv; acc[mt][nt][1] = bv;
      acc[mt][nt][2] = bv; acc[mt][nt][3] = bv;
    }
  }
#pragma unroll
  for (int ks = 0; ks < KD; ks++) {
    bf16x8 a[MT];
#pragma unroll
    for (int mt = 0; mt < MT; mt++)
      a[mt] = *(const bf16x8*)(X + (rowOff + mt * 16 + c) * xs + ks * 32 + q * 8);
    bf16x8 bb[4];
#pragma unroll
    for (int nt = 0; nt < 4; nt++)
      bb[nt] = *(const bf16x8*)(Wp + ((((wc * 4 + nt) * KD + ks) * 64 + lane) << 3));
#pragma unroll
    for (int mt = 0; mt < MT; mt++)
#pragma unroll
      for (int nt = 0; nt < 4; nt++)
        acc[mt][nt] = MFMA16(a[mt], bb[nt], acc[mt][nt]);
  }
}

template <int KD, int MT, bool RELU>
__device__ __forceinline__ void layer_inplace(bf16* X, int xs_r, int xs_w,
                                              const bf16* __restrict__ Wp,
                                              const float* __restrict__ bias,
                                              int rowOff, int wc) {
  f32x4 acc[MT][4];
  layer_acc<KD, MT>(X, xs_r, Wp, bias, acc, rowOff, wc);
  const int lane = threadIdx.x & 63;
  const int q = lane >> 4;
  const int c = lane & 15;
  __syncthreads();  // all waves done reading X before overwrite
#pragma unroll
  for (int mt = 0; mt < MT; mt++)
#pragma unroll
    for (int nt = 0; nt < 4; nt++)
#pragma unroll
      for (int i = 0; i < 4; i++) {
        float v = acc[mt][nt][i];
        if (RELU) v = fmaxf(v, 0.0f);
        X[(rowOff + mt * 16 + q * 4 + i) * xs_w + (wc * 64 + nt * 16 + c)] = (bf16)v;
      }
  __syncthreads();
}

// ---------------- S+P producer: one staged tile, two GEMMs ----------------
// 256 blocks x 64 rows: S = nodes@Wa + e_fb ; P = nodes@Wb. Direct acc->global.
__global__ __launch_bounds__(512, 4) void producer_sp(
    const float* __restrict__ nodes, const bf16* __restrict__ w_self,
    const bf16* __restrict__ w_nb, const float* __restrict__ e_fb,
    bf16* __restrict__ Sb, bf16* __restrict__ Pb) {
  __shared__ bf16 X[64 * 280];
  const int t = threadIdx.x;
  const int m0 = blockIdx.x * 64;
  {
    const int r = t >> 3;   // 64 rows, 8 threads/row
    const int q8 = t & 7;
#pragma unroll
    for (int c8 = 0; c8 < 4; c8++) {
      int col = q8 * 8 + c8 * 64;
      float4 f0 = *(const float4*)(nodes + (m0 + r) * 256 + col);
      float4 f1 = *(const float4*)(nodes + (m0 + r) * 256 + col + 4);
      bf16x8 v;
      v[0] = (bf16)f0.x; v[1] = (bf16)f0.y; v[2] = (bf16)f0.z; v[3] = (bf16)f0.w;
      v[4] = (bf16)f1.x; v[5] = (bf16)f1.y; v[6] = (bf16)f1.z; v[7] = (bf16)f1.w;
      *(bf16x8*)(X + r * 280 + col) = v;
    }
  }
  __syncthreads();
  const int lane = t & 63;
  const int w = t >> 6;
  const int wc = w & 3;
  const int rowOff = (w >> 2) * 32;
  const int q = lane >> 4;
  const int c = lane & 15;
  f32x4 acc[2][4];
  layer_acc<8, 2>(X, 280, w_self, e_fb, acc, rowOff, wc);
#pragma unroll
  for (int mt = 0; mt < 2; mt++)
#pragma unroll
    for (int nt = 0; nt < 4; nt++)
#pragma unroll
      for (int i = 0; i < 4; i++)
        Sb[(m0 + rowOff + mt * 16 + q * 4 + i) * 256 + wc * 64 + nt * 16 + c] =
            (bf16)acc[mt][nt][i];
  layer_acc<8, 2>(X, 280, w_nb, nullptr, acc, rowOff, wc);
#pragma unroll
  for (int mt = 0; mt < 2; mt++)
#pragma unroll
    for (int nt = 0; nt < 4; nt++)
#pragma unroll
      for (int i = 0; i < 4; i++)
        Pb[(m0 + rowOff + mt * 16 + q * 4 + i) * 256 + wc * 64 + nt * 16 + c] =
            (bf16)acc[mt][nt][i];
}

// ---------------- fused edge MLP: inline E + layers 2..4 + aggregation ------
// Block = 4 points x 16 v x 2 batches = 128 rows. E (64 rows) computed once,
// shared by both batches. X rows 0-63 = b0 edges, 64-127 = b1 edges
// (E staged/computed in rows 64-127 before assembly overwrites them).
__global__ __launch_bounds__(512, 4) void edge_mlp(
    const bf16* __restrict__ S, const bf16* __restrict__ P,
    const float* __restrict__ eattr, const int* __restrict__ idx,
    const bf16* __restrict__ w_ea, const bf16* __restrict__ Wh0,
    const bf16* __restrict__ Wh1, const bf16* __restrict__ Wl,
    const float* __restrict__ e_hb, const float* __restrict__ e_lb,
    bf16* __restrict__ agg, float* __restrict__ out_edges) {
  __shared__ bf16 X[128 * 280];
  const int t = threadIdx.x;
  const int pbase = blockIdx.x * 4;  // 2048 blocks
  // ---- stage eattr (64 rows fp32) into X rows 64..127 as bf16
  {
    const int r = t >> 3;   // 0..63, 8 threads/row
    const int q8 = t & 7;   // 32 fp32 cols each (128B contiguous per thread)
    const float* src = eattr + (pbase * 16 + r) * 256 + q8 * 32;
    bf16* dst = X + (64 + r) * 280 + q8 * 32;
#pragma unroll
    for (int h = 0; h < 4; h++) {
      float4 f0 = *(const float4*)(src + h * 8);
      float4 f1 = *(const float4*)(src + h * 8 + 4);
      bf16x8 v;
      v[0] = (bf16)f0.x; v[1] = (bf16)f0.y; v[2] = (bf16)f0.z; v[3] = (bf16)f0.w;
      v[4] = (bf16)f1.x; v[5] = (bf16)f1.y; v[6] = (bf16)f1.z; v[7] = (bf16)f1.w;
      *(bf16x8*)(dst + h * 8) = v;
    }
  }
  __syncthreads();
  const int lane = t & 63;
  const int w = t >> 6;
  const int wc = w & 3;
  const int rg = w >> 2;
  const int q = lane >> 4;
  const int c = lane & 15;
  // ---- inline E-GEMM over the 64 staged rows (E = eattr @ Wc, no bias)
  {
    f32x4 acce[2][4];
    layer_acc<8, 2>(X, 280, w_ea, nullptr, acce, 64 + rg * 32, wc);
    __syncthreads();  // all A-frag reads done before in-place E write
#pragma unroll
    for (int mt = 0; mt < 2; mt++)
#pragma unroll
      for (int nt = 0; nt < 4; nt++)
#pragma unroll
        for (int i = 0; i < 4; i++)
          X[(64 + rg * 32 + mt * 16 + q * 4 + i) * 280 + wc * 64 + nt * 16 + c] =
              (bf16)acce[mt][nt][i];
  }
  __syncthreads();
  // ---- assemble relu(S + Pgather + E) for both batches (rows 0..127)
  {
    const int r = t >> 2;     // 0..127
    const int q4 = t & 3;     // 64 cols each
    const int b = r >> 6;
    const int rr = r & 63;
    const int p = pbase + (rr >> 4);
    const int v = rr & 15;
    const int nb = idx[p * kNV + v];
    const bf16* Srow = S + ((b << 13) + p) * 256;
    const bf16* Prow = P + ((b << 13) + nb) * 256;
    bf16x8 hold[8];
#pragma unroll
    for (int j = 0; j < 8; j++) {
      int col = q4 * 64 + j * 8;
      bf16x8 ev = *(const bf16x8*)(X + (64 + rr) * 280 + col);
      bf16x8 sv = *(const bf16x8*)(Srow + col);
      bf16x8 pv = *(const bf16x8*)(Prow + col);
      bf16x8 o;
#pragma unroll
      for (int k = 0; k < 8; k++) {
        float f = (float)sv[k] + (float)pv[k] + (float)ev[k];
        o[k] = (bf16)fmaxf(f, 0.0f);
      }
      hold[j] = o;
    }
    __syncthreads();  // E reads done everywhere before rows are overwritten
#pragma unroll
    for (int j = 0; j < 8; j++)
      *(bf16x8*)(X + r * 280 + q4 * 64 + j * 8) = hold[j];
  }
  __syncthreads();
  // ---- hidden layers + last layer (MT=4: wave covers 64 rows)
  layer_inplace<8, 4, true>(X, 280, 280, Wh0, e_hb, rg * 64, wc);
  layer_inplace<8, 4, true>(X, 280, 280, Wh1, e_hb + 256, rg * 64, wc);
  f32x4 acc[4][4];
  layer_acc<8, 4>(X, 280, Wl, e_lb, acc, rg * 64, wc);
  // ---- NV-aggregation: tile g = rg*4+mt -> batch g>>2, point pbase+(g&3)
#pragma unroll
  for (int mt = 0; mt < 4; mt++) {
    const int g = rg * 4 + mt;
#pragma unroll
    for (int nt = 0; nt < 4; nt++) {
      float s = acc[mt][nt][0] + acc[mt][nt][1] + acc[mt][nt][2] + acc[mt][nt][3];
      s += __shfl_xor(s, 16, 64);
      s += __shfl_xor(s, 32, 64);
      if (lane < 16)
        agg[(((g >> 2) << 13) + pbase + (g & 3)) * 256 + wc * 64 + nt * 16 + lane] =
            (bf16)s;
    }
  }
  // ---- batch-0 edge outputs (rows 0..63 = rg 0)
  if (rg == 0) {
#pragma unroll
    for (int mt = 0; mt < 4; mt++)
#pragma unroll
      for (int nt = 0; nt < 4; nt++)
#pragma unroll
        for (int i = 0; i < 4; i++) {
          int e = (pbase + mt) * kNV + q * 4 + i;
          out_edges[e * 256 + wc * 64 + nt * 16 + c] = acc[mt][nt][i];
        }
  }
}

// ---------------- fused node MLP + residual ----------------
// 64-row tiles, 512 threads (8 waves: 2 row-groups x 4 col-groups, MT=2).
__global__ __launch_bounds__(512, 4) void node_mlp(
    const float* __restrict__ nodes, const bf16* __restrict__ agg,
    const bf16* __restrict__ Wf, const bf16* __restrict__ Wh0,
    const bf16* __restrict__ Wh1, const bf16* __restrict__ Wl,
    const float* __restrict__ n_fb, const float* __restrict__ n_hb,
    const float* __restrict__ n_lb, float* __restrict__ out_nodes) {
  __shared__ bf16 X[64 * 536];
  const int t = threadIdx.x;
  const int r = t >> 3;   // 64 rows, 8 threads/row
  const int q8 = t & 7;
  const int m = blockIdx.x * 64 + r;
#pragma unroll
  for (int c8 = 0; c8 < 8; c8++) {
    int col = q8 * 8 + c8 * 64;  // 0..511; <256 from nodes, >=256 from agg
    if (col < 256) {
      float4 f0 = *(const float4*)(nodes + m * 256 + col);
      float4 f1 = *(const float4*)(nodes + m * 256 + col + 4);
      bf16x8 v;
      v[0] = (bf16)f0.x; v[1] = (bf16)f0.y; v[2] = (bf16)f0.z; v[3] = (bf16)f0.w;
      v[4] = (bf16)f1.x; v[5] = (bf16)f1.y; v[6] = (bf16)f1.z; v[7] = (bf16)f1.w;
      *(bf16x8*)(X + r * 536 + col) = v;
    } else {
      *(bf16x8*)(X + r * 536 + col) =
          *(const bf16x8*)(agg + m * 256 + (col - 256));
    }
  }
  __syncthreads();
  const int w = t >> 6;
  const int wc = w & 3;
  const int rowOff = (w >> 2) * 32;
  layer_inplace<16, 2, true>(X, 536, 280, Wf, n_fb, rowOff, wc);
  layer_inplace<8, 2, true>(X, 280, 280, Wh0, n_hb, rowOff, wc);
  layer_inplace<8, 2, true>(X, 280, 280, Wh1, n_hb + 256, rowOff, wc);
  f32x4 acc[2][4];
  layer_acc<8, 2>(X, 280, Wl, n_lb, acc, rowOff, wc);
  const int lane = t & 63;
  const int q = lane >> 4;
  const int c = lane & 15;
#pragma unroll
  for (int mt = 0; mt < 2; mt++)
#pragma unroll
    for (int nt = 0; nt < 4; nt++)
#pragma unroll
      for (int i = 0; i < 4; i++) {
        int mm = blockIdx.x * 64 + rowOff + mt * 16 + q * 4 + i;
        int col = wc * 64 + nt * 16 + c;
        out_nodes[mm * 256 + col] = nodes[mm * 256 + col] + acc[mt][nt][i];
      }
}

// ---------------- launch ----------------
extern "C" void kernel_launch(void* const* d_in, const int* in_sizes, int n_in,
                              void* d_out, int out_size, void* d_ws,
                              size_t ws_size, hipStream_t stream) {
  const float* nodes = (const float*)d_in[0];
  const float* eattr = (const float*)d_in[1];
  const int* eidx = (const int*)d_in[2];
  const float* e_fw = (const float*)d_in[3];
  const float* e_fb = (const float*)d_in[4];
  const float* e_hw = (const float*)d_in[5];
  const float* e_hb = (const float*)d_in[6];
  const float* e_lw = (const float*)d_in[7];
  const float* e_lb = (const float*)d_in[8];
  const float* n_fw = (const float*)d_in[9];
  const float* n_fb = (const float*)d_in[10];
  const float* n_hw = (const float*)d_in[11];
  const float* n_hb = (const float*)d_in[12];
  const float* n_lw = (const float*)d_in[13];
  const float* n_lb = (const float*)d_in[14];

  // workspace map (bytes); total ~26.6 MB
  char* ws = (char*)d_ws;
  bf16* Sb = (bf16*)(ws + 0);            // [16384][256]
  bf16* Pb = (bf16*)(ws + 8388608);      // [16384][256]
  bf16* aggb = (bf16*)(ws + 16777216);   // [16384][256]
  bf16* wp = (bf16*)(ws + 25165824);     // packed-weight arena, 720896 elems
  bf16* w_self = wp;
  bf16* w_nb = wp + 65536;
  bf16* w_ea = wp + 131072;
  bf16* w_eh0 = wp + 196608;
  bf16* w_eh1 = wp + 262144;
  bf16* w_el = wp + 327680;
  bf16* w_nf = wp + 393216;              // 131072 elems (K=512)
  bf16* w_nh0 = wp + 524288;
  bf16* w_nh1 = wp + 589824;
  bf16* w_nl = wp + 655360;

  float* out_nodes = (float*)d_out;
  float* out_edges = (float*)d_out + 4194304;  // after [B,NP,NL] nodes

  pack_all<<<2816, 256, 0, stream>>>(e_fw, e_hw, e_lw, n_fw, n_hw, n_lw, wp);
  producer_sp<<<256, 512, 0, stream>>>(nodes, w_self, w_nb, e_fb, Sb, Pb);
  edge_mlp<<<2048, 512, 0, stream>>>(Sb, Pb, eattr, eidx, w_ea, w_eh0, w_eh1,
                                     w_el, e_hb, e_lb, aggb, out_edges);
  node_mlp<<<256, 512, 0, stream>>>(nodes, aggb, w_nf, w_nh0, w_nh1, w_nl,
                                    n_fb, n_hb, n_lb, out_nodes);
}